// Round 3
// baseline (113.726 us; speedup 1.0000x reference)
//
#include <hip/hip_runtime.h>

#define B_ 32
#define C_ 64          // Cin = Cout = 64
#define H_ 112
#define W_ 112
#define HW (H_ * W_)
#define ROWS 2
#define HTILES (H_ / ROWS)   // 56
#define NBLK (B_ * HTILES)   // 1792

// LDS x-tile: [4 rows][114 cols][40 bf16 slots] -- 32 cin (one phase) = 64 B
// content + 16 B pad, spatial stride 80 B (20 dwords).
//  - ds_read_b128 B-frag: dword off = lcol*20 + kg*4 (mod 32) -> uniform
//    8 lanes per quad-bank-group -> minimal cycles.
//  - staging ds_write_b32: lanes vary cp (16 banks) then col (+16 mod 32)
//    -> exactly 2-way -> free.
// 36480 B -> 4 blocks/CU (vs 65.6 KB / 2 blocks in round 2).
#define XC 114
#define SPSTR 80
#define LDS_SH (4 * XC * SPSTR / 2)   // shorts

typedef short bf16x8 __attribute__((ext_vector_type(8)));
typedef float f32x4 __attribute__((ext_vector_type(4)));

__device__ inline unsigned short f2bf(float f) {
    union { float f; unsigned u; } v;
    v.f = f;
    unsigned u = v.u;
    u += 0x7fffu + ((u >> 16) & 1u);   // RNE
    return (unsigned short)(u >> 16);
}

// w[co][cin][kh][kw] fp32 -> wq[shift][co][cin] bf16 sign
__global__ void quant_w(const float* __restrict__ w,
                        unsigned short* __restrict__ wq) {
    int i = blockIdx.x * 256 + threadIdx.x;
    if (i >= C_ * C_ * 9) return;
    int k   = i % 9;
    int cin = (i / 9) % C_;
    int co  = i / (9 * C_);
    float v = w[i];
    float q = (v > 0.f) ? 1.f : ((v < 0.f) ? -1.f : 0.f);
    wq[(k * C_ + co) * C_ + cin] = f2bf(q);
}

__global__ __launch_bounds__(256, 4) void conv_mfma(
    const float* __restrict__ x, const unsigned short* __restrict__ wq,
    const float* __restrict__ bias, const float* __restrict__ scale,
    float* __restrict__ out) {
    __shared__ unsigned short xs[LDS_SH];

    const int tid  = threadIdx.x;
    const int lane = tid & 63;
    const int wave = tid >> 6;
    const int lcol = lane & 15;
    const int kg   = lane >> 4;

    // XCD-bijective swizzle (NBLK % 8 == 0)
    const int bid = blockIdx.x;
    const int s   = (bid & 7) * (NBLK / 8) + (bid >> 3);
    const int b   = s / HTILES;
    const int h0  = (s % HTILES) * ROWS;

    const float* xb = x + (size_t)b * C_ * HW;
    char* xsb = (char*)xs;

    // one-time zero of the 2 halo columns (slots 0 and 113, 64 B each, 4 rows)
    if (tid < 32) {
        const int r = tid >> 3, sl = (tid >> 2) & 1, q = tid & 3;
        *(f32x4*)(xsb + (r * XC + sl * 113) * SPSTR + q * 16) =
            (f32x4){0.f, 0.f, 0.f, 0.f};
    }

    // N-fragment offsets: nf = wave + 4*i over 14 frags (2 rows x 7 colgroups)
    int nfoff[4];
#pragma unroll
    for (int i = 0; i < 4; ++i) {
        const int nf  = wave + 4 * i;
        const int nfr = (nf >= 7) ? 1 : 0;
        const int nfc = nf - 7 * nfr;
        nfoff[i] = (nfr * XC + nfc * 16) * SPSTR;
    }

    f32x4 acc[4][4];
#pragma unroll
    for (int m = 0; m < 4; ++m)
#pragma unroll
        for (int i = 0; i < 4; ++i) acc[m][i] = (f32x4){0.f, 0.f, 0.f, 0.f};

    for (int ph = 0; ph < 2; ++ph) {
        if (ph) __syncthreads();   // compute(ph-1) reads done before overwrite

        // ---- stage 32 cins (this phase), 4 rows x 112 cols, transposed ----
#pragma unroll 2
        for (int it = 0; it < 7; ++it) {
            const int u    = tid + 256 * it;        // 0..1791
            const int cp   = u & 15;                // cin pair in phase
            const int cg   = (u >> 4) % 28;         // 4-col group
            const int r    = u / 448;               // LDS row 0..3
            const int xrow = h0 - 1 + r;
            const int col  = cg * 4;
            const int cin0 = ph * 32 + 2 * cp;

            float4 a = make_float4(0.f, 0.f, 0.f, 0.f);
            float4 c = make_float4(0.f, 0.f, 0.f, 0.f);
            if (0 <= xrow && xrow < H_) {
                const float* p = xb + (size_t)cin0 * HW + xrow * W_ + col;
                a = *(const float4*)p;
                c = *(const float4*)(p + HW);
            }
            char* wp = xsb + (r * XC + col + 1) * SPSTR + cp * 4;
            *(unsigned*)(wp) =
                (unsigned)f2bf(a.x) | ((unsigned)f2bf(c.x) << 16);
            *(unsigned*)(wp + SPSTR) =
                (unsigned)f2bf(a.y) | ((unsigned)f2bf(c.y) << 16);
            *(unsigned*)(wp + 2 * SPSTR) =
                (unsigned)f2bf(a.z) | ((unsigned)f2bf(c.z) << 16);
            *(unsigned*)(wp + 3 * SPSTR) =
                (unsigned)f2bf(a.w) | ((unsigned)f2bf(c.w) << 16);
        }
        __syncthreads();

        // ---- compute: 9 shifts x K=32 (this phase's cins) ----
#pragma unroll
        for (int dh = -1; dh <= 1; ++dh) {
#pragma unroll
            for (int dw = -1; dw <= 1; ++dw) {
                const unsigned short* wbase = wq +
                    ((dh + 1) * 3 + (dw + 1)) * C_ * C_ + lcol * C_ +
                    ph * 32 + kg * 8;
                const bf16x8 af0 = *(const bf16x8*)(wbase);
                const bf16x8 af1 = *(const bf16x8*)(wbase + 16 * C_);
                const bf16x8 af2 = *(const bf16x8*)(wbase + 32 * C_);
                const bf16x8 af3 = *(const bf16x8*)(wbase + 48 * C_);
                const int soff =
                    ((1 + dh) * XC + (lcol + 1) + dw) * SPSTR + kg * 16;
#pragma unroll
                for (int i = 0; i < 4; ++i) {
                    if (wave + 4 * i < 14) {   // wave-uniform guard
                        const bf16x8 bv =
                            *(const bf16x8*)(xsb + soff + nfoff[i]);
                        acc[0][i] = __builtin_amdgcn_mfma_f32_16x16x32_bf16(
                            af0, bv, acc[0][i], 0, 0, 0);
                        acc[1][i] = __builtin_amdgcn_mfma_f32_16x16x32_bf16(
                            af1, bv, acc[1][i], 0, 0, 0);
                        acc[2][i] = __builtin_amdgcn_mfma_f32_16x16x32_bf16(
                            af2, bv, acc[2][i], 0, 0, 0);
                        acc[3][i] = __builtin_amdgcn_mfma_f32_16x16x32_bf16(
                            af3, bv, acc[3][i], 0, 0, 0);
                    }
                }
            }
        }
    }

    // ---- epilogue ----
    const float sc = scale[0];
    f32x4 bv[4];
#pragma unroll
    for (int m = 0; m < 4; ++m)
        bv[m] = *(const f32x4*)(bias + m * 16 + kg * 4);

#pragma unroll
    for (int i = 0; i < 4; ++i) {
        const int nf = wave + 4 * i;
        if (nf < 14) {
            const int nfr  = (nf >= 7) ? 1 : 0;
            const int nfc  = nf - 7 * nfr;
            const int h    = h0 + nfr;
            const int colb = nfc * 16 + lcol;
#pragma unroll
            for (int m = 0; m < 4; ++m)
#pragma unroll
                for (int r = 0; r < 4; ++r) {
                    const int cout = m * 16 + kg * 4 + r;
                    out[((size_t)b * C_ + cout) * HW + h * W_ + colb] =
                        sc * (acc[m][i][r] + bv[m][r]);
                }
        }
    }
}

extern "C" void kernel_launch(void* const* d_in, const int* in_sizes, int n_in,
                              void* d_out, int out_size, void* d_ws,
                              size_t ws_size, hipStream_t stream) {
    const float* x     = (const float*)d_in[0];
    const float* w     = (const float*)d_in[1];
    const float* bias  = (const float*)d_in[2];
    const float* scale = (const float*)d_in[3];
    float* out         = (float*)d_out;

    unsigned short* wq = (unsigned short*)d_ws;   // 73728 B

    quant_w<<<(C_ * C_ * 9 + 255) / 256, 256, 0, stream>>>(w, wq);
    conv_mfma<<<NBLK, 256, 0, stream>>>(x, wq, bias, scale, out);
}

// Round 4
// 90.607 us; speedup vs baseline: 1.2552x; 1.2552x over previous
//
#include <hip/hip_runtime.h>

#define B_ 32
#define C_ 64          // Cin = Cout
#define H_ 112
#define W_ 112
#define HW (H_ * W_)
#define ROWS 2
#define HTILES (H_ / ROWS)   // 56
#define NBLK (B_ * HTILES)   // 1792

#define SLOTS 114            // slot = w+1, w in [-1,112]; slots 0,113 = zeros
#define CHUNK 128            // bytes per (h,slot) chunk: 64 cin bf16
#define XROWB (SLOTS * CHUNK)              // 14592 B per (b,h)
#define XT_BYTES ((size_t)B_ * H_ * XROWB) // 52,297,728
#define WQ_OFF 131072                       // xt starts after wq region

typedef short bf16x8 __attribute__((ext_vector_type(8)));
typedef float f32x4 __attribute__((ext_vector_type(4)));
typedef unsigned int u32;

#define GLOAD_LDS(g, l, sz)                                                   \
    __builtin_amdgcn_global_load_lds(                                         \
        (const __attribute__((address_space(1))) u32*)(const void*)(g),       \
        (__attribute__((address_space(3))) u32*)(void*)(l), (sz), 0, 0)

__device__ inline unsigned short f2bf(float f) {
    union { float f; unsigned u; } v;
    v.f = f;
    unsigned u = v.u;
    u += 0x7fffu + ((u >> 16) & 1u);   // RNE
    return (unsigned short)(u >> 16);
}

// w[co][cin][kh][kw] fp32 -> wq[shift][co][cin] bf16 sign
__global__ void quant_w(const float* __restrict__ w,
                        unsigned short* __restrict__ wq) {
    int i = blockIdx.x * 256 + threadIdx.x;
    if (i >= C_ * C_ * 9) return;
    int k   = i % 9;
    int cin = (i / 9) % C_;
    int co  = i / (9 * C_);
    float v = w[i];
    float q = (v > 0.f) ? 1.f : ((v < 0.f) ? -1.f : 0.f);
    wq[(k * C_ + co) * C_ + cin] = f2bf(q);
}

// ---------------------------------------------------------------------------
// Transform: x[b][c][h][w] fp32 -> xt[b][h][slot][cin] bf16, pre-swizzled:
// within each 128-B chunk, the dword for cin-pair cp lives at (cp*4)^((slot&7)<<4).
// Block = one (b,h). Planar LDS transpose, all phases conflict-free+coalesced.
// ---------------------------------------------------------------------------
__global__ __launch_bounds__(256) void xform(const float* __restrict__ x,
                                             unsigned short* __restrict__ xt) {
    __shared__ unsigned short pl[C_ * SLOTS];   // planar [c][114], use [c*114+w]

    const int tid = threadIdx.x;
    const int b   = blockIdx.x / H_;
    const int h   = blockIdx.x % H_;

    // phase 1: coalesced float4 reads (lanes->w), planar LDS writes (free)
#pragma unroll
    for (int it = 0; it < 7; ++it) {
        const int u  = tid + 256 * it;        // < 1792 = 64c * 28 quads
        const int c  = u / 28;
        const int w4 = u % 28;
        const f32x4 v = *(const f32x4*)(x + ((size_t)(b * C_ + c) * H_ + h) * W_ + w4 * 4);
        const u32 lo = (u32)f2bf(v[0]) | ((u32)f2bf(v[1]) << 16);
        const u32 hi = (u32)f2bf(v[2]) | ((u32)f2bf(v[3]) << 16);
        u32* p = (u32*)&pl[c * SLOTS + w4 * 4];   // byte 228c+8w4, dword-aligned
        p[0] = lo;
        p[1] = hi;
    }
    __syncthreads();

    // phase 2: LDS gather (lanes->c, 2-way max), coalesced dword global writes
    unsigned short* xtrow = xt + (size_t)(b * H_ + h) * (XROWB / 2);
#pragma unroll
    for (int it = 0; it < 15; ++it) {
        const int u = tid + 256 * it;         // < 3648 = 114 slots * 32 cps
        if (u < SLOTS * 32) {
            const int slot = u >> 5;
            const int cp   = u & 31;
            u32 val = 0;
            if (1 <= slot && slot <= 112) {
                const int w = slot - 1;
                val = (u32)pl[(2 * cp) * SLOTS + w] |
                      ((u32)pl[(2 * cp + 1) * SLOTS + w] << 16);
            }
            *(u32*)((char*)xtrow + slot * CHUNK +
                    ((cp * 4) ^ ((slot & 7) << 4))) = val;
        }
    }
}

// ---------------------------------------------------------------------------
// Conv as implicit GEMM, m97-style: global_load_lds staging (linear LDS,
// source pre-swizzled), one barrier, MFMA-dense K-loop.
// Block = (b, 2 output rows). Waves 2x2 split (mw: cout-half, nw: row).
// Per wave: acc[2 m][7 nf], 18 K-steps x {2 A-loads(L2), 7 ds_read_b128, 14 MFMA}.
// ---------------------------------------------------------------------------
__global__ __launch_bounds__(256) void conv_mfma(
    const unsigned short* __restrict__ xt, const unsigned short* __restrict__ wq,
    const float* __restrict__ bias, const float* __restrict__ scale,
    float* __restrict__ out) {
    __shared__ char xs[4 * XROWB];   // 58368 B

    const int tid  = threadIdx.x;
    const int lane = tid & 63;
    const int wave = tid >> 6;
    const int lcol = lane & 15;
    const int kg   = lane >> 4;
    const int mw   = wave >> 1;
    const int nw   = wave & 1;

    const int bid = blockIdx.x;
    const int s   = (bid & 7) * (NBLK / 8) + (bid >> 3);   // XCD-bijective
    const int b   = s / HTILES;
    const int h0  = (s % HTILES) * ROWS;

    // ---- stage: wave r copies xt row h0-1+r linearly into LDS ----
    {
        const int r    = wave;
        const int xrow = h0 - 1 + r;
        char* dst = xs + r * XROWB;
        if (0 <= xrow && xrow < H_) {
            const char* src =
                (const char*)xt + (size_t)(b * H_ + xrow) * XROWB + lane * 16;
#pragma unroll
            for (int ch = 0; ch < 14; ++ch)
                GLOAD_LDS(src + ch * 1024, dst + ch * 1024, 16);
            GLOAD_LDS((const char*)xt + (size_t)(b * H_ + xrow) * XROWB +
                          14336 + lane * 4,
                      dst + 14336, 4);
        } else {
            char* d = dst + lane * 16;
            const f32x4 z = {0.f, 0.f, 0.f, 0.f};
#pragma unroll
            for (int ch = 0; ch < 14; ++ch) *(f32x4*)(d + ch * 1024) = z;
            *(u32*)(dst + 14336 + lane * 4) = 0u;
        }
    }
    __syncthreads();

    // swizzle-adjusted K-offsets: addr = base + ((c0*64 + kg*16) ^ key(dw))
    int koff[3][2];
#pragma unroll
    for (int dw = 0; dw < 3; ++dw) {
        const int key = ((lcol + dw) & 7) << 4;
        koff[dw][0] = (kg * 16) ^ key;
        koff[dw][1] = (64 + kg * 16) ^ key;
    }

    f32x4 acc[2][7];
#pragma unroll
    for (int m = 0; m < 2; ++m)
#pragma unroll
        for (int nf = 0; nf < 7; ++nf) acc[m][nf] = (f32x4){0.f, 0.f, 0.f, 0.f};

    const unsigned short* wqa = wq + (mw * 32 + lcol) * C_ + kg * 8;

#pragma unroll
    for (int dh = 0; dh < 3; ++dh) {
        const char* rowb = xs + (nw + dh) * XROWB;
#pragma unroll
        for (int dw = 0; dw < 3; ++dw) {
            const unsigned short* wsft = wqa + (dh * 3 + dw) * (C_ * C_);
            const char* colb = rowb + (lcol + dw) * CHUNK;
#pragma unroll
            for (int c0 = 0; c0 < 2; ++c0) {
                const bf16x8 a0 = *(const bf16x8*)(wsft + c0 * 32);
                const bf16x8 a1 = *(const bf16x8*)(wsft + 16 * C_ + c0 * 32);
                const char* cb = colb + koff[dw][c0];
#pragma unroll
                for (int nf = 0; nf < 7; ++nf) {
                    const bf16x8 bv = *(const bf16x8*)(cb + nf * 2048);
                    acc[0][nf] = __builtin_amdgcn_mfma_f32_16x16x32_bf16(
                        a0, bv, acc[0][nf], 0, 0, 0);
                    acc[1][nf] = __builtin_amdgcn_mfma_f32_16x16x32_bf16(
                        a1, bv, acc[1][nf], 0, 0, 0);
                }
            }
        }
    }

    // ---- epilogue ----
    const float sc = scale[0];
    const int h = h0 + nw;
#pragma unroll
    for (int m = 0; m < 2; ++m) {
        const int cobase = mw * 32 + m * 16 + kg * 4;
        const f32x4 bs = *(const f32x4*)(bias + cobase);
#pragma unroll
        for (int nf = 0; nf < 7; ++nf) {
            const int col = nf * 16 + lcol;
#pragma unroll
            for (int rr = 0; rr < 4; ++rr)
                out[((size_t)(b * C_ + cobase + rr)) * HW + h * W_ + col] =
                    sc * (acc[m][nf][rr] + bs[rr]);
        }
    }
}

// ---------------------------------------------------------------------------
// Fallback (ws too small for xt): round-3 single-kernel path.
// ---------------------------------------------------------------------------
#define XCF 114
#define SPSTRF 80
#define LDS_SHF (4 * XCF * SPSTRF / 2)

__global__ __launch_bounds__(256, 4) void conv_mfma_fb(
    const float* __restrict__ x, const unsigned short* __restrict__ wq,
    const float* __restrict__ bias, const float* __restrict__ scale,
    float* __restrict__ out) {
    __shared__ unsigned short xss[LDS_SHF];
    const int tid = threadIdx.x, lane = tid & 63, wave = tid >> 6;
    const int lcol = lane & 15, kg = lane >> 4;
    const int bid = blockIdx.x;
    const int s = (bid & 7) * (NBLK / 8) + (bid >> 3);
    const int b = s / HTILES, h0 = (s % HTILES) * ROWS;
    const float* xb = x + (size_t)b * C_ * HW;
    char* xsb = (char*)xss;
    if (tid < 32) {
        const int r = tid >> 3, sl = (tid >> 2) & 1, q = tid & 3;
        *(f32x4*)(xsb + (r * XCF + sl * 113) * SPSTRF + q * 16) =
            (f32x4){0.f, 0.f, 0.f, 0.f};
    }
    int nfoff[4];
#pragma unroll
    for (int i = 0; i < 4; ++i) {
        const int nf = wave + 4 * i, nfr = (nf >= 7) ? 1 : 0;
        nfoff[i] = (nfr * XCF + (nf - 7 * nfr) * 16) * SPSTRF;
    }
    f32x4 acc[4][4];
#pragma unroll
    for (int m = 0; m < 4; ++m)
#pragma unroll
        for (int i = 0; i < 4; ++i) acc[m][i] = (f32x4){0.f, 0.f, 0.f, 0.f};
    for (int ph = 0; ph < 2; ++ph) {
        if (ph) __syncthreads();
#pragma unroll 2
        for (int it = 0; it < 7; ++it) {
            const int u = tid + 256 * it;
            const int cp = u & 15, cg = (u >> 4) % 28, r = u / 448;
            const int xrow = h0 - 1 + r, col = cg * 4, cin0 = ph * 32 + 2 * cp;
            float4 a = make_float4(0, 0, 0, 0), c = make_float4(0, 0, 0, 0);
            if (0 <= xrow && xrow < H_) {
                const float* p = xb + (size_t)cin0 * HW + xrow * W_ + col;
                a = *(const float4*)p;
                c = *(const float4*)(p + HW);
            }
            char* wp = xsb + (r * XCF + col + 1) * SPSTRF + cp * 4;
            *(u32*)(wp) = (u32)f2bf(a.x) | ((u32)f2bf(c.x) << 16);
            *(u32*)(wp + SPSTRF) = (u32)f2bf(a.y) | ((u32)f2bf(c.y) << 16);
            *(u32*)(wp + 2 * SPSTRF) = (u32)f2bf(a.z) | ((u32)f2bf(c.z) << 16);
            *(u32*)(wp + 3 * SPSTRF) = (u32)f2bf(a.w) | ((u32)f2bf(c.w) << 16);
        }
        __syncthreads();
#pragma unroll
        for (int dh = -1; dh <= 1; ++dh)
#pragma unroll
            for (int dw = -1; dw <= 1; ++dw) {
                const unsigned short* wbase = wq +
                    ((dh + 1) * 3 + (dw + 1)) * C_ * C_ + lcol * C_ +
                    ph * 32 + kg * 8;
                const bf16x8 af0 = *(const bf16x8*)(wbase);
                const bf16x8 af1 = *(const bf16x8*)(wbase + 16 * C_);
                const bf16x8 af2 = *(const bf16x8*)(wbase + 32 * C_);
                const bf16x8 af3 = *(const bf16x8*)(wbase + 48 * C_);
                const int soff =
                    ((1 + dh) * XCF + (lcol + 1) + dw) * SPSTRF + kg * 16;
#pragma unroll
                for (int i = 0; i < 4; ++i)
                    if (wave + 4 * i < 14) {
                        const bf16x8 bv =
                            *(const bf16x8*)(xsb + soff + nfoff[i]);
                        acc[0][i] = __builtin_amdgcn_mfma_f32_16x16x32_bf16(
                            af0, bv, acc[0][i], 0, 0, 0);
                        acc[1][i] = __builtin_amdgcn_mfma_f32_16x16x32_bf16(
                            af1, bv, acc[1][i], 0, 0, 0);
                        acc[2][i] = __builtin_amdgcn_mfma_f32_16x16x32_bf16(
                            af2, bv, acc[2][i], 0, 0, 0);
                        acc[3][i] = __builtin_amdgcn_mfma_f32_16x16x32_bf16(
                            af3, bv, acc[3][i], 0, 0, 0);
                    }
            }
    }
    const float sc = scale[0];
    f32x4 bv[4];
#pragma unroll
    for (int m = 0; m < 4; ++m)
        bv[m] = *(const f32x4*)(bias + m * 16 + kg * 4);
#pragma unroll
    for (int i = 0; i < 4; ++i) {
        const int nf = wave + 4 * i;
        if (nf < 14) {
            const int nfr = (nf >= 7) ? 1 : 0;
            const int h = h0 + nfr, colb = (nf - 7 * nfr) * 16 + lcol;
#pragma unroll
            for (int m = 0; m < 4; ++m)
#pragma unroll
                for (int rr = 0; rr < 4; ++rr)
                    out[((size_t)b * C_ + m * 16 + kg * 4 + rr) * HW +
                        h * W_ + colb] = sc * (acc[m][i][rr] + bv[m][rr]);
        }
    }
}

extern "C" void kernel_launch(void* const* d_in, const int* in_sizes, int n_in,
                              void* d_out, int out_size, void* d_ws,
                              size_t ws_size, hipStream_t stream) {
    const float* x     = (const float*)d_in[0];
    const float* w     = (const float*)d_in[1];
    const float* bias  = (const float*)d_in[2];
    const float* scale = (const float*)d_in[3];
    float* out         = (float*)d_out;

    unsigned short* wq = (unsigned short*)d_ws;   // 73728 B

    quant_w<<<(C_ * C_ * 9 + 255) / 256, 256, 0, stream>>>(w, wq);

    if (ws_size >= WQ_OFF + XT_BYTES) {
        unsigned short* xt = (unsigned short*)((char*)d_ws + WQ_OFF);
        xform<<<B_ * H_, 256, 0, stream>>>(x, xt);
        conv_mfma<<<NBLK, 256, 0, stream>>>(xt, wq, bias, scale, out);
    } else {
        conv_mfma_fb<<<NBLK, 256, 0, stream>>>(x, wq, bias, scale, out);
    }
}